// Round 1
// baseline (455.894 us; speedup 1.0000x reference)
//
#include <hip/hip_runtime.h>
#include <cstdint>
#include <cstddef>

// B=64, S=2048, H=512.  M = B*S = 131072 rows.
#define B_DIM 64
#define S_DIM 2048
#define H_DIM 512

typedef __attribute__((ext_vector_type(8))) short short8;   // 8 bf16 = 4 VGPR
typedef __attribute__((ext_vector_type(4))) float f32x4;    // MFMA 16x16 accum

static __device__ __forceinline__ unsigned short f2bf(float f) {
  union { float f; unsigned int u; } v; v.f = f;
  unsigned int r = (v.u + 0x7fffu + ((v.u >> 16) & 1u)) >> 16;  // RNE
  return (unsigned short)r;
}

static __device__ __forceinline__ float fast_tanh(float x) {
  x = fminf(15.f, fmaxf(-15.f, x));
  float e = __expf(x + x);
  return 1.f - 2.f * __builtin_amdgcn_rcpf(e + 1.f);
}

// ---- convert first 512 cols of W[512][1024] (keys part) to bf16 [512][512]
__global__ __launch_bounds__(256) void convw_kernel(
    const float* __restrict__ W1, const float* __restrict__ W2,
    unsigned short* __restrict__ wk1, unsigned short* __restrict__ wk2) {
  int idx = blockIdx.x * 256 + threadIdx.x;            // 0 .. 524287
  const float* W = (idx < 262144) ? W1 : W2;
  unsigned short* o = (idx < 262144) ? wk1 : wk2;
  int j = idx & 262143;
  int d = j >> 9, h = j & 511;
  o[j] = f2bf(W[(size_t)d * 1024 + h]);
}

// ---- qp[b][d] = sum_h W[d][512+h] * x[b][h]   (query-half matvec)
__global__ __launch_bounds__(512) void qproj_kernel(
    const float* __restrict__ W, const float* __restrict__ x,
    float* __restrict__ qp) {
  __shared__ float xs[512];
  int b = blockIdx.x, d = threadIdx.x;
  xs[d] = x[b * 512 + d];
  __syncthreads();
  const float* wr = W + (size_t)d * 1024 + 512;
  float acc = 0.f;
  #pragma unroll 8
  for (int h = 0; h < 512; ++h) acc += wr[h] * xs[h];
  qp[b * 512 + d] = acc;
}

// ---- fused scores: out[r] = sum_d v[d] * tanh( keys[r,:]·wk[d,:] + qp[b,d] )
// Block = 64 rows (one batch each, 2048/64=32 blocks per b), 4 waves.
// keys tile [64][512] staged once as bf16 in LDS (XOR-swizzled, G4).
// Wave w owns cols w*32..w*32+31 of each 128-col n-tile; K=512 fully looped.
__global__ __launch_bounds__(256, 2) void fused_scores_kernel(
    const float* __restrict__ keys, const unsigned short* __restrict__ wk,
    const float* __restrict__ v, const float* __restrict__ qp,
    float* __restrict__ out) {
  __shared__ __align__(16) unsigned short lds_k[64 * 512];   // 64 KB
  __shared__ float lds_score[4][64];
  char* lds_b = (char*)lds_k;

  const int tid  = threadIdx.x;
  const int wid  = tid >> 6;
  const int lane = tid & 63;
  const int l15  = lane & 15;
  const int lhi  = lane >> 4;              // 0..3
  const int row0 = blockIdx.x * 64;
  const int b    = row0 >> 11;             // row0 / 2048

  // -------- stage keys[row0..row0+63][0..511] f32 -> bf16 LDS (swizzled)
  #pragma unroll 4
  for (int it = 0; it < 32; ++it) {
    int e = (it * 256 + tid) * 4;          // element index in 64x512 tile
    int r = e >> 9, k = e & 511;
    const float4 f = *reinterpret_cast<const float4*>(
        keys + (size_t)(row0 + r) * 512 + k);
    ushort4 h4;
    h4.x = f2bf(f.x); h4.y = f2bf(f.y); h4.z = f2bf(f.z); h4.w = f2bf(f.w);
    int byte = (r * 1024 + k * 2) ^ ((r & 7) << 4);
    *reinterpret_cast<ushort4*>(lds_b + byte) = h4;
  }
  __syncthreads();

  float rp[4][4];                          // per-lane row partials: row = mr*16+lhi*4+j
  #pragma unroll
  for (int mr = 0; mr < 4; ++mr)
    #pragma unroll
    for (int j = 0; j < 4; ++j) rp[mr][j] = 0.f;

  const int koff_lane = lhi * 8;

  #pragma unroll 1
  for (int nt = 0; nt < 4; ++nt) {
    const int d_base = nt * 128 + wid * 32;
    f32x4 acc[4][2];
    #pragma unroll
    for (int mr = 0; mr < 4; ++mr)
      #pragma unroll
      for (int nc = 0; nc < 2; ++nc) {
        f32x4 z = {0.f, 0.f, 0.f, 0.f};
        acc[mr][nc] = z;
      }

    #pragma unroll 4
    for (int k0 = 0; k0 < 512; k0 += 32) {
      short8 a[4], bfr[2];
      #pragma unroll
      for (int mr = 0; mr < 4; ++mr) {
        int r = mr * 16 + l15;
        int byte = (r * 1024 + (k0 + koff_lane) * 2) ^ ((r & 7) << 4);
        a[mr] = *reinterpret_cast<const short8*>(lds_b + byte);
      }
      #pragma unroll
      for (int nc = 0; nc < 2; ++nc) {
        const unsigned short* p =
            wk + (((size_t)(d_base + nc * 16 + l15)) << 9) + k0 + koff_lane;
        bfr[nc] = *reinterpret_cast<const short8*>(p);
      }
      #pragma unroll
      for (int mr = 0; mr < 4; ++mr)
        #pragma unroll
        for (int nc = 0; nc < 2; ++nc)
          acc[mr][nc] = __builtin_amdgcn_mfma_f32_16x16x32_bf16(
              a[mr], bfr[nc], acc[mr][nc], 0, 0, 0);
    }

    // epilogue: tanh(acc + qp) * v, accumulate per-row
    #pragma unroll
    for (int nc = 0; nc < 2; ++nc) {
      int col = d_base + nc * 16 + l15;
      float vv = v[col];
      float qv = qp[b * 512 + col];
      #pragma unroll
      for (int mr = 0; mr < 4; ++mr)
        #pragma unroll
        for (int j = 0; j < 4; ++j)
          rp[mr][j] += fast_tanh(acc[mr][nc][j] + qv) * vv;
    }
  }

  // reduce over the 16 cols held across lanes l15=0..15 (same lhi group)
  #pragma unroll
  for (int off = 1; off < 16; off <<= 1)
    #pragma unroll
    for (int mr = 0; mr < 4; ++mr)
      #pragma unroll
      for (int j = 0; j < 4; ++j)
        rp[mr][j] += __shfl_xor(rp[mr][j], off, 64);

  if (l15 == 0) {
    #pragma unroll
    for (int mr = 0; mr < 4; ++mr)
      #pragma unroll
      for (int j = 0; j < 4; ++j)
        lds_score[wid][mr * 16 + lhi * 4 + j] = rp[mr][j];
  }
  __syncthreads();
  if (tid < 64)
    out[row0 + tid] = lds_score[0][tid] + lds_score[1][tid] +
                      lds_score[2][tid] + lds_score[3][tid];
}

// ---- softmax over S per batch row (in place)
__global__ __launch_bounds__(256) void softmax_kernel(float* __restrict__ sc) {
  int b = blockIdx.x, tid = threadIdx.x;
  float* row = sc + (size_t)b * S_DIM;
  float vv[8];
  float m = -1e30f;
  #pragma unroll
  for (int i = 0; i < 8; ++i) { vv[i] = row[tid + i * 256]; m = fmaxf(m, vv[i]); }
  #pragma unroll
  for (int off = 32; off; off >>= 1) m = fmaxf(m, __shfl_xor(m, off, 64));
  __shared__ float red[4], red2[4];
  int wid = tid >> 6, lane = tid & 63;
  if (lane == 0) red[wid] = m;
  __syncthreads();
  m = fmaxf(fmaxf(red[0], red[1]), fmaxf(red[2], red[3]));
  float s = 0.f;
  #pragma unroll
  for (int i = 0; i < 8; ++i) { vv[i] = __expf(vv[i] - m); s += vv[i]; }
  #pragma unroll
  for (int off = 32; off; off >>= 1) s += __shfl_xor(s, off, 64);
  if (lane == 0) red2[wid] = s;
  __syncthreads();
  s = red2[0] + red2[1] + red2[2] + red2[3];
  float inv = 1.f / s;
  #pragma unroll
  for (int i = 0; i < 8; ++i) row[tid + i * 256] = vv[i] * inv;
}

// ---- new_q partials: part[b][sc][h] = sum_{s in chunk} attn[b,s]*keys[b,s,h]
__global__ __launch_bounds__(512) void wsum_part_kernel(
    const float* __restrict__ keys, const float* __restrict__ attn,
    float* __restrict__ part) {
  int b = blockIdx.x, sc = blockIdx.y, h = threadIdx.x;
  const float* kb = keys + ((size_t)b * S_DIM + sc * 128) * 512 + h;
  const float* ab = attn + b * S_DIM + sc * 128;
  float acc = 0.f;
  #pragma unroll 4
  for (int i = 0; i < 128; ++i) acc += ab[i] * kb[(size_t)i * 512];
  part[((size_t)b * 16 + sc) * 512 + h] = acc;
}

// ---- deterministic final reduce: new_q[b][h] = sum_sc part[b][sc][h]
__global__ __launch_bounds__(512) void wsum_final_kernel(
    const float* __restrict__ part, float* __restrict__ new_q) {
  int b = blockIdx.x, h = threadIdx.x;
  float acc = 0.f;
  #pragma unroll
  for (int sc = 0; sc < 16; ++sc) acc += part[((size_t)b * 16 + sc) * 512 + h];
  new_q[b * 512 + h] = acc;
}

extern "C" void kernel_launch(void* const* d_in, const int* in_sizes, int n_in,
                              void* d_out, int out_size, void* d_ws, size_t ws_size,
                              hipStream_t stream) {
  (void)in_sizes; (void)n_in; (void)out_size; (void)ws_size;
  const float* keys  = (const float*)d_in[0];
  const float* query = (const float*)d_in[1];
  const float* v1    = (const float*)d_in[2];
  const float* W1    = (const float*)d_in[3];
  const float* v2    = (const float*)d_in[4];
  const float* W2    = (const float*)d_in[5];
  float* out = (float*)d_out;

  // workspace layout (floats): qp1 | attn | new_q | qp2 | part | wk1,wk2 (bf16)
  float* wsf   = (float*)d_ws;
  float* qp1   = wsf;                 // 32768
  float* attn  = wsf + 32768;         // 131072 (scores1 -> softmax in place)
  float* new_q = wsf + 163840;        // 32768
  float* qp2   = wsf + 196608;        // 32768
  float* part  = wsf + 229376;        // 524288
  unsigned short* wk1 = (unsigned short*)(wsf + 753664);  // 262144 ushorts
  unsigned short* wk2 = wk1 + 262144;                     // total ws ~3.9 MB

  convw_kernel<<<2048, 256, 0, stream>>>(W1, W2, wk1, wk2);
  qproj_kernel<<<64, 512, 0, stream>>>(W1, query, qp1);
  fused_scores_kernel<<<2048, 256, 0, stream>>>(keys, wk1, v1, qp1, attn);
  softmax_kernel<<<64, 256, 0, stream>>>(attn);
  wsum_part_kernel<<<dim3(64, 16), 512, 0, stream>>>(keys, attn, part);
  wsum_final_kernel<<<64, 512, 0, stream>>>(part, new_q);
  qproj_kernel<<<64, 512, 0, stream>>>(W2, new_q, qp2);
  fused_scores_kernel<<<2048, 256, 0, stream>>>(keys, wk2, v2, qp2, out);
}

// Round 2
// 408.689 us; speedup vs baseline: 1.1155x; 1.1155x over previous
//
#include <hip/hip_runtime.h>
#include <cstdint>
#include <cstddef>

// B=64, S=2048, H=512.  M = B*S = 131072 rows.
#define S_DIM 2048

typedef __attribute__((ext_vector_type(8))) short short8;   // 8 bf16 = 4 VGPR
typedef __attribute__((ext_vector_type(4))) float f32x4;    // MFMA 16x16 accum

static __device__ __forceinline__ unsigned short f2bf(float f) {
  union { float f; unsigned int u; } v; v.f = f;
  unsigned int r = (v.u + 0x7fffu + ((v.u >> 16) & 1u)) >> 16;  // RNE
  return (unsigned short)r;
}

static __device__ __forceinline__ float fast_tanh(float x) {
  x = fminf(15.f, fmaxf(-15.f, x));
  float e = __expf(x + x);
  return 1.f - 2.f * __builtin_amdgcn_rcpf(e + 1.f);
}

// ---- convert first 512 cols of W[512][1024] (keys part) to bf16 [512][512]
__global__ __launch_bounds__(256) void convw_kernel(
    const float* __restrict__ W1, const float* __restrict__ W2,
    unsigned short* __restrict__ wk1, unsigned short* __restrict__ wk2) {
  int idx = blockIdx.x * 256 + threadIdx.x;            // 0 .. 524287
  const float* W = (idx < 262144) ? W1 : W2;
  unsigned short* o = (idx < 262144) ? wk1 : wk2;
  int j = idx & 262143;
  int d = j >> 9, h = j & 511;
  o[j] = f2bf(W[(size_t)d * 1024 + h]);
}

// ---- qp[b][d] = sum_h W[d][512+h] * x[b][h]   (query-half matvec)
__global__ __launch_bounds__(512) void qproj_kernel(
    const float* __restrict__ W, const float* __restrict__ x,
    float* __restrict__ qp) {
  __shared__ float xs[512];
  int b = blockIdx.x, d = threadIdx.x;
  xs[d] = x[b * 512 + d];
  __syncthreads();
  const float4* wr = (const float4*)(W + (size_t)d * 1024 + 512);
  const float4* xv = (const float4*)xs;
  float acc = 0.f;
  #pragma unroll 8
  for (int h = 0; h < 128; ++h) {
    float4 w4 = wr[h], x4 = xv[h];
    acc += w4.x * x4.x + w4.y * x4.y + w4.z * x4.z + w4.w * x4.w;
  }
  qp[b * 512 + d] = acc;
}

// ---- fused scores: out[r] = sum_d v[d] * tanh( keys[r,:]·wk[d,:] + qp[b,d] )
// Block = 64 rows x full N=512, K=512. 8 waves; wave w owns cols w*64..w*64+63.
// keys tile [64][512] bf16 in LDS (XOR-swizzled); B streams from L2.
__global__ __launch_bounds__(512, 4) void fused_scores_kernel(
    const float* __restrict__ keys, const unsigned short* __restrict__ wk,
    const float* __restrict__ v, const float* __restrict__ qp,
    float* __restrict__ out) {
  __shared__ __align__(16) unsigned short lds_k[64 * 512];   // 64 KB
  __shared__ float lds_score[8][64];
  char* lds_b = (char*)lds_k;

  const int tid  = threadIdx.x;
  const int wid  = tid >> 6;
  const int lane = tid & 63;
  const int l15  = lane & 15;
  const int lhi  = lane >> 4;              // 0..3
  const int row0 = blockIdx.x * 64;
  const int b    = row0 >> 11;             // row0 / 2048
  const int wcol = wid * 64;

  // -------- stage keys[row0..row0+63][0..511] f32 -> bf16 LDS (swizzled)
  // Each thread handles 8 elem chunks of 8: full-row 16B writes, conflict-free.
  #pragma unroll
  for (int i = 0; i < 8; ++i) {
    int c = i * 512 + tid;                 // 8-elem chunk index, 4096 total
    int r = c >> 6, k = (c & 63) * 8;
    const float* src = keys + (size_t)(row0 + r) * 512 + k;
    const float4 f0 = *reinterpret_cast<const float4*>(src);
    const float4 f1 = *reinterpret_cast<const float4*>(src + 4);
    short8 hv;
    hv[0] = (short)f2bf(f0.x); hv[1] = (short)f2bf(f0.y);
    hv[2] = (short)f2bf(f0.z); hv[3] = (short)f2bf(f0.w);
    hv[4] = (short)f2bf(f1.x); hv[5] = (short)f2bf(f1.y);
    hv[6] = (short)f2bf(f1.z); hv[7] = (short)f2bf(f1.w);
    int byte = (r * 1024 + k * 2) ^ ((r & 7) << 4);
    *reinterpret_cast<short8*>(lds_b + byte) = hv;
  }
  __syncthreads();

  f32x4 acc[4][4];
  #pragma unroll
  for (int mr = 0; mr < 4; ++mr)
    #pragma unroll
    for (int nc = 0; nc < 4; ++nc) {
      f32x4 z = {0.f, 0.f, 0.f, 0.f};
      acc[mr][nc] = z;
    }

  const int koff = lhi * 8;

  #pragma unroll 1
  for (int k0 = 0; k0 < 512; k0 += 32) {
    short8 a[4], bb[4];
    #pragma unroll
    for (int nc = 0; nc < 4; ++nc) {
      const unsigned short* p =
          wk + (((size_t)(wcol + nc * 16 + l15)) << 9) + k0 + koff;
      bb[nc] = *reinterpret_cast<const short8*>(p);
    }
    #pragma unroll
    for (int mr = 0; mr < 4; ++mr) {
      int r = mr * 16 + l15;
      int byte = (r * 1024 + (k0 + koff) * 2) ^ ((r & 7) << 4);
      a[mr] = *reinterpret_cast<const short8*>(lds_b + byte);
    }
    #pragma unroll
    for (int mr = 0; mr < 4; ++mr)
      #pragma unroll
      for (int nc = 0; nc < 4; ++nc)
        acc[mr][nc] = __builtin_amdgcn_mfma_f32_16x16x32_bf16(
            a[mr], bb[nc], acc[mr][nc], 0, 0, 0);
  }

  // epilogue: tanh(acc + qp) * v, accumulate per-row partials
  float rp[4][4];
  #pragma unroll
  for (int mr = 0; mr < 4; ++mr)
    #pragma unroll
    for (int j = 0; j < 4; ++j) rp[mr][j] = 0.f;

  #pragma unroll
  for (int nc = 0; nc < 4; ++nc) {
    int col = wcol + nc * 16 + l15;
    float vv = v[col];
    float qv = qp[b * 512 + col];
    #pragma unroll
    for (int mr = 0; mr < 4; ++mr)
      #pragma unroll
      for (int j = 0; j < 4; ++j)
        rp[mr][j] += fast_tanh(acc[mr][nc][j] + qv) * vv;
  }

  // reduce over the 16 cols held across lanes l15=0..15 (same lhi group)
  #pragma unroll
  for (int off = 1; off < 16; off <<= 1)
    #pragma unroll
    for (int mr = 0; mr < 4; ++mr)
      #pragma unroll
      for (int j = 0; j < 4; ++j)
        rp[mr][j] += __shfl_xor(rp[mr][j], off, 64);

  if (l15 == 0) {
    #pragma unroll
    for (int mr = 0; mr < 4; ++mr)
      #pragma unroll
      for (int j = 0; j < 4; ++j)
        lds_score[wid][mr * 16 + lhi * 4 + j] = rp[mr][j];
  }
  __syncthreads();
  if (tid < 64) {
    float s = 0.f;
    #pragma unroll
    for (int w = 0; w < 8; ++w) s += lds_score[w][tid];
    out[row0 + tid] = s;
  }
}

// ---- softmax over S per batch row (in place)
__global__ __launch_bounds__(256) void softmax_kernel(float* __restrict__ sc) {
  int b = blockIdx.x, tid = threadIdx.x;
  float* row = sc + (size_t)b * S_DIM;
  float vv[8];
  float m = -1e30f;
  #pragma unroll
  for (int i = 0; i < 8; ++i) { vv[i] = row[tid + i * 256]; m = fmaxf(m, vv[i]); }
  #pragma unroll
  for (int off = 32; off; off >>= 1) m = fmaxf(m, __shfl_xor(m, off, 64));
  __shared__ float red[4], red2[4];
  int wid = tid >> 6, lane = tid & 63;
  if (lane == 0) red[wid] = m;
  __syncthreads();
  m = fmaxf(fmaxf(red[0], red[1]), fmaxf(red[2], red[3]));
  float s = 0.f;
  #pragma unroll
  for (int i = 0; i < 8; ++i) { vv[i] = __expf(vv[i] - m); s += vv[i]; }
  #pragma unroll
  for (int off = 32; off; off >>= 1) s += __shfl_xor(s, off, 64);
  if (lane == 0) red2[wid] = s;
  __syncthreads();
  s = red2[0] + red2[1] + red2[2] + red2[3];
  float inv = 1.f / s;
  #pragma unroll
  for (int i = 0; i < 8; ++i) row[tid + i * 256] = vv[i] * inv;
}

// ---- new_q partials: part[b][sc][:] = sum_{s in 128-chunk} attn[b,s]*keys[b,s,:]
// float4 lanes: tid = rg*128 + c4, rg owns 32 rows.
__global__ __launch_bounds__(512) void wsum_part_kernel(
    const float* __restrict__ keys, const float* __restrict__ attn,
    float* __restrict__ part) {
  int b = blockIdx.x, sc = blockIdx.y;
  int tid = threadIdx.x;
  int c4 = tid & 127, rg = tid >> 7;
  const float* kb = keys + ((size_t)(b * S_DIM + sc * 128 + rg * 32)) * 512 + c4 * 4;
  const float* ab = attn + b * S_DIM + sc * 128 + rg * 32;
  float4 acc = {0.f, 0.f, 0.f, 0.f};
  #pragma unroll 8
  for (int i = 0; i < 32; ++i) {
    float w = ab[i];
    float4 kv = *reinterpret_cast<const float4*>(kb + (size_t)i * 512);
    acc.x += w * kv.x; acc.y += w * kv.y; acc.z += w * kv.z; acc.w += w * kv.w;
  }
  __shared__ float4 red[4][128];
  red[rg][c4] = acc;
  __syncthreads();
  if (tid < 128) {
    float4 a0 = red[0][tid], a1 = red[1][tid], a2 = red[2][tid], a3 = red[3][tid];
    float4 s;
    s.x = a0.x + a1.x + a2.x + a3.x;
    s.y = a0.y + a1.y + a2.y + a3.y;
    s.z = a0.z + a1.z + a2.z + a3.z;
    s.w = a0.w + a1.w + a2.w + a3.w;
    *reinterpret_cast<float4*>(part + ((size_t)b * 16 + sc) * 512 + tid * 4) = s;
  }
}

// ---- deterministic final reduce: new_q[b][h] = sum_sc part[b][sc][h]
__global__ __launch_bounds__(512) void wsum_final_kernel(
    const float* __restrict__ part, float* __restrict__ new_q) {
  int b = blockIdx.x, h = threadIdx.x;
  float acc = 0.f;
  #pragma unroll
  for (int sc = 0; sc < 16; ++sc) acc += part[((size_t)b * 16 + sc) * 512 + h];
  new_q[b * 512 + h] = acc;
}

extern "C" void kernel_launch(void* const* d_in, const int* in_sizes, int n_in,
                              void* d_out, int out_size, void* d_ws, size_t ws_size,
                              hipStream_t stream) {
  (void)in_sizes; (void)n_in; (void)out_size; (void)ws_size;
  const float* keys  = (const float*)d_in[0];
  const float* query = (const float*)d_in[1];
  const float* v1    = (const float*)d_in[2];
  const float* W1    = (const float*)d_in[3];
  const float* v2    = (const float*)d_in[4];
  const float* W2    = (const float*)d_in[5];
  float* out = (float*)d_out;

  // workspace layout (floats): qp1 | attn | new_q | qp2 | part | wk1,wk2 (bf16)
  float* wsf   = (float*)d_ws;
  float* qp1   = wsf;                 // 32768
  float* attn  = wsf + 32768;         // 131072 (scores1 -> softmax in place)
  float* new_q = wsf + 163840;        // 32768
  float* qp2   = wsf + 196608;        // 32768
  float* part  = wsf + 229376;        // 524288
  unsigned short* wk1 = (unsigned short*)(wsf + 753664);  // 262144 ushorts
  unsigned short* wk2 = wk1 + 262144;                     // total ws ~3.9 MB

  convw_kernel<<<2048, 256, 0, stream>>>(W1, W2, wk1, wk2);
  qproj_kernel<<<64, 512, 0, stream>>>(W1, query, qp1);
  fused_scores_kernel<<<2048, 512, 0, stream>>>(keys, wk1, v1, qp1, attn);
  softmax_kernel<<<64, 256, 0, stream>>>(attn);
  wsum_part_kernel<<<dim3(64, 16), 512, 0, stream>>>(keys, attn, part);
  wsum_final_kernel<<<64, 512, 0, stream>>>(part, new_q);
  qproj_kernel<<<64, 512, 0, stream>>>(W2, new_q, qp2);
  fused_scores_kernel<<<2048, 512, 0, stream>>>(keys, wk2, v2, qp2, out);
}

// Round 3
// 304.955 us; speedup vs baseline: 1.4950x; 1.3402x over previous
//
#include <hip/hip_runtime.h>
#include <cstdint>
#include <cstddef>

// B=64, S=2048, H=512.  M = B*S = 131072 rows.
#define S_DIM 2048

typedef __attribute__((ext_vector_type(8))) short short8;   // 8 bf16 = 4 VGPR
typedef __attribute__((ext_vector_type(4))) float f32x4;    // MFMA 16x16 accum

static __device__ __forceinline__ unsigned short f2bf(float f) {
  union { float f; unsigned int u; } v; v.f = f;
  unsigned int r = (v.u + 0x7fffu + ((v.u >> 16) & 1u)) >> 16;  // RNE
  return (unsigned short)r;
}

static __device__ __forceinline__ float bf2f(unsigned short u) {
  union { unsigned int u; float f; } v; v.u = ((unsigned int)u) << 16;
  return v.f;
}

static __device__ __forceinline__ float fast_tanh(float x) {
  x = fminf(15.f, fmaxf(-15.f, x));
  float e = __expf(x + x);
  return 1.f - 2.f * __builtin_amdgcn_rcpf(e + 1.f);
}

static __device__ __forceinline__ void gload_lds16(const void* g, void* l) {
  __builtin_amdgcn_global_load_lds(
      (const __attribute__((address_space(1))) void*)g,
      (__attribute__((address_space(3))) void*)l, 16, 0, 0);
}

// =====================  FAST PATH (packed layouts)  =====================
// Packed A (keys bf16): per 64-row tile t (2048 tiles):
//   elem offset = t*32768 + k0*2048 + mr*512 + lhi*128 + l15*8 + e
//   value = keys[t*64 + mr*16 + l15][k0*32 + lhi*8 + e]
// Packed B (wk bf16): elem offset = k0*16384 + g*512 + lhi*128 + l15*8 + e
//   value = W[g*16 + l15][k0*32 + lhi*8 + e]   (keys-half of W, row stride 1024)

__global__ __launch_bounds__(256) void pack_a_kernel(
    const float* __restrict__ keys, unsigned short* __restrict__ akp) {
  int gid = blockIdx.x * 256 + threadIdx.x;          // 0 .. 8388607
  int tile = gid >> 12;
  int wt = gid & 4095;
  int k0 = wt >> 8, mr = (wt >> 6) & 3, lhi = (wt >> 4) & 3, l15 = wt & 15;
  const float* src = keys + (size_t)(tile * 64 + mr * 16 + l15) * 512 + k0 * 32 + lhi * 8;
  float4 f0 = *reinterpret_cast<const float4*>(src);
  float4 f1 = *reinterpret_cast<const float4*>(src + 4);
  short8 hv;
  hv[0] = (short)f2bf(f0.x); hv[1] = (short)f2bf(f0.y);
  hv[2] = (short)f2bf(f0.z); hv[3] = (short)f2bf(f0.w);
  hv[4] = (short)f2bf(f1.x); hv[5] = (short)f2bf(f1.y);
  hv[6] = (short)f2bf(f1.z); hv[7] = (short)f2bf(f1.w);
  *reinterpret_cast<short8*>(akp + (size_t)gid * 8) = hv;
}

__global__ __launch_bounds__(256) void pack_b_kernel(
    const float* __restrict__ W1, const float* __restrict__ W2,
    unsigned short* __restrict__ wkp1, unsigned short* __restrict__ wkp2) {
  int j = blockIdx.x * 256 + threadIdx.x;            // 0 .. 65535
  const float* W = (j < 32768) ? W1 : W2;
  unsigned short* o = (j < 32768) ? wkp1 : wkp2;
  int wt = j & 32767;
  int k0 = wt >> 11, g = (wt >> 6) & 31, lhi = (wt >> 4) & 3, l15 = wt & 15;
  const float* src = W + (size_t)(g * 16 + l15) * 1024 + k0 * 32 + lhi * 8;
  float4 f0 = *reinterpret_cast<const float4*>(src);
  float4 f1 = *reinterpret_cast<const float4*>(src + 4);
  short8 hv;
  hv[0] = (short)f2bf(f0.x); hv[1] = (short)f2bf(f0.y);
  hv[2] = (short)f2bf(f0.z); hv[3] = (short)f2bf(f0.w);
  hv[4] = (short)f2bf(f1.x); hv[5] = (short)f2bf(f1.y);
  hv[6] = (short)f2bf(f1.z); hv[7] = (short)f2bf(f1.w);
  *reinterpret_cast<short8*>(o + (size_t)wt * 8) = hv;
}

// fused scores from packed operands. Block = 64 rows x 512 cols, 8 waves.
__global__ __launch_bounds__(512, 4) void fused_packed_kernel(
    const unsigned short* __restrict__ akp, const unsigned short* __restrict__ wkp,
    const float* __restrict__ v, const float* __restrict__ qp,
    float* __restrict__ out) {
  __shared__ __align__(16) unsigned short lds_a[32768];   // 64 KB packed A tile
  __shared__ float lds_score[8][64];

  const int tid  = threadIdx.x;
  const int wid  = tid >> 6;
  const int lane = tid & 63;
  const int l15  = lane & 15;
  const int lhi  = lane >> 4;
  const int tile = blockIdx.x;
  const int row0 = tile * 64;
  const int b    = row0 >> 11;
  const int wcol = wid * 64;

  // stage packed A tile via async global->LDS (linear, conflict-free)
  const unsigned short* atile = akp + (size_t)tile * 32768;
  #pragma unroll
  for (int i = 0; i < 8; ++i)
    gload_lds16(atile + (i * 512 + tid) * 8, (char*)lds_a + (i * 512 + tid) * 16);

  // prefetch B fragments for k0 = 0 (fully coalesced 1KB per wave per frag)
  const unsigned short* wbase = wkp + (size_t)wid * 2048 + (size_t)lane * 8;
  short8 bb[2][4];
  #pragma unroll
  for (int nc = 0; nc < 4; ++nc)
    bb[0][nc] = *reinterpret_cast<const short8*>(wbase + nc * 512);

  __syncthreads();   // drains vmcnt(0): LDS image + bb[0] ready

  f32x4 acc[4][4];
  #pragma unroll
  for (int mr = 0; mr < 4; ++mr)
    #pragma unroll
    for (int nc = 0; nc < 4; ++nc) {
      f32x4 z = {0.f, 0.f, 0.f, 0.f};
      acc[mr][nc] = z;
    }

  const char* abase = (const char*)lds_a + lane * 16;

  #pragma unroll
  for (int k0 = 0; k0 < 16; ++k0) {
    const int cur = k0 & 1, nxt = cur ^ 1;
    if (k0 < 15) {
      #pragma unroll
      for (int nc = 0; nc < 4; ++nc)
        bb[nxt][nc] = *reinterpret_cast<const short8*>(
            wbase + (size_t)(k0 + 1) * 16384 + nc * 512);
    }
    short8 a[4];
    #pragma unroll
    for (int mr = 0; mr < 4; ++mr)
      a[mr] = *reinterpret_cast<const short8*>(abase + k0 * 4096 + mr * 1024);
    #pragma unroll
    for (int mr = 0; mr < 4; ++mr)
      #pragma unroll
      for (int nc = 0; nc < 4; ++nc)
        acc[mr][nc] = __builtin_amdgcn_mfma_f32_16x16x32_bf16(
            a[mr], bb[cur][nc], acc[mr][nc], 0, 0, 0);
  }

  // epilogue: tanh(acc + qp) * v, accumulate per-row partials
  float rp[4][4];
  #pragma unroll
  for (int mr = 0; mr < 4; ++mr)
    #pragma unroll
    for (int j = 0; j < 4; ++j) rp[mr][j] = 0.f;

  #pragma unroll
  for (int nc = 0; nc < 4; ++nc) {
    int col = wcol + nc * 16 + l15;
    float vv = v[col];
    float qv = qp[b * 512 + col];
    #pragma unroll
    for (int mr = 0; mr < 4; ++mr)
      #pragma unroll
      for (int j = 0; j < 4; ++j)
        rp[mr][j] += fast_tanh(acc[mr][nc][j] + qv) * vv;
  }

  #pragma unroll
  for (int off = 1; off < 16; off <<= 1)
    #pragma unroll
    for (int mr = 0; mr < 4; ++mr)
      #pragma unroll
      for (int j = 0; j < 4; ++j)
        rp[mr][j] += __shfl_xor(rp[mr][j], off, 64);

  if (l15 == 0) {
    #pragma unroll
    for (int mr = 0; mr < 4; ++mr)
      #pragma unroll
      for (int j = 0; j < 4; ++j)
        lds_score[wid][mr * 16 + lhi * 4 + j] = rp[mr][j];
  }
  __syncthreads();
  if (tid < 64) {
    float s = 0.f;
    #pragma unroll
    for (int w = 0; w < 8; ++w) s += lds_score[w][tid];
    out[row0 + tid] = s;
  }
}

// new_q[b][h] = sum_s attn[b,s] * keys[b,s,h], reading packed bf16 keys.
// grid (b, k0); block handles h in [k0*32, k0*32+32).
__global__ __launch_bounds__(256) void wsum_packed_kernel(
    const unsigned short* __restrict__ akp, const float* __restrict__ attn,
    float* __restrict__ new_q) {
  int b = blockIdx.x, k0 = blockIdx.y;
  int t = threadIdx.x;
  int mr = t >> 6, lhi = (t >> 4) & 3, l15 = t & 15;
  const unsigned short* base =
      akp + (size_t)b * 32 * 32768 + (size_t)k0 * 2048 + (size_t)t * 8;
  const float* ab = attn + b * S_DIM + mr * 16 + l15;
  float acc[8];
  #pragma unroll
  for (int e = 0; e < 8; ++e) acc[e] = 0.f;
  #pragma unroll 4
  for (int tile = 0; tile < 32; ++tile) {
    short8 kv = *reinterpret_cast<const short8*>(base + (size_t)tile * 32768);
    float w = ab[tile * 64];
    #pragma unroll
    for (int e = 0; e < 8; ++e)
      acc[e] += w * bf2f((unsigned short)kv[e]);
  }
  __shared__ float red[4][64][8];   // [lhi][row-slot][e]
  #pragma unroll
  for (int e = 0; e < 8; ++e) red[lhi][mr * 16 + l15][e] = acc[e];
  __syncthreads();
  if (t < 32) {
    int lh = t >> 3, e = t & 7;
    float s = 0.f;
    #pragma unroll 8
    for (int r = 0; r < 64; ++r) s += red[lh][r][e];
    new_q[b * 512 + k0 * 32 + lh * 8 + e] = s;
  }
}

// =====================  SHARED KERNELS  =====================

// qp[b][d] = sum_h W[d][512+h] * x[b][h]
__global__ __launch_bounds__(512) void qproj_kernel(
    const float* __restrict__ W, const float* __restrict__ x,
    float* __restrict__ qp) {
  __shared__ float xs[512];
  int b = blockIdx.x, d = threadIdx.x;
  xs[d] = x[b * 512 + d];
  __syncthreads();
  const float4* wr = (const float4*)(W + (size_t)d * 1024 + 512);
  const float4* xv = (const float4*)xs;
  float acc = 0.f;
  #pragma unroll 8
  for (int h = 0; h < 128; ++h) {
    float4 w4 = wr[h], x4 = xv[h];
    acc += w4.x * x4.x + w4.y * x4.y + w4.z * x4.z + w4.w * x4.w;
  }
  qp[b * 512 + d] = acc;
}

__global__ __launch_bounds__(256) void softmax_kernel(float* __restrict__ sc) {
  int b = blockIdx.x, tid = threadIdx.x;
  float* row = sc + (size_t)b * S_DIM;
  float vv[8];
  float m = -1e30f;
  #pragma unroll
  for (int i = 0; i < 8; ++i) { vv[i] = row[tid + i * 256]; m = fmaxf(m, vv[i]); }
  #pragma unroll
  for (int off = 32; off; off >>= 1) m = fmaxf(m, __shfl_xor(m, off, 64));
  __shared__ float red[4], red2[4];
  int wid = tid >> 6, lane = tid & 63;
  if (lane == 0) red[wid] = m;
  __syncthreads();
  m = fmaxf(fmaxf(red[0], red[1]), fmaxf(red[2], red[3]));
  float s = 0.f;
  #pragma unroll
  for (int i = 0; i < 8; ++i) { vv[i] = __expf(vv[i] - m); s += vv[i]; }
  #pragma unroll
  for (int off = 32; off; off >>= 1) s += __shfl_xor(s, off, 64);
  if (lane == 0) red2[wid] = s;
  __syncthreads();
  s = red2[0] + red2[1] + red2[2] + red2[3];
  float inv = 1.f / s;
  #pragma unroll
  for (int i = 0; i < 8; ++i) row[tid + i * 256] = vv[i] * inv;
}

// =====================  FALLBACK PATH (round-2, f32 keys)  =====================

__global__ __launch_bounds__(256) void convw_kernel(
    const float* __restrict__ W1, const float* __restrict__ W2,
    unsigned short* __restrict__ wk1, unsigned short* __restrict__ wk2) {
  int idx = blockIdx.x * 256 + threadIdx.x;
  const float* W = (idx < 262144) ? W1 : W2;
  unsigned short* o = (idx < 262144) ? wk1 : wk2;
  int j = idx & 262143;
  int d = j >> 9, h = j & 511;
  o[j] = f2bf(W[(size_t)d * 1024 + h]);
}

__global__ __launch_bounds__(512, 4) void fused_scores_kernel(
    const float* __restrict__ keys, const unsigned short* __restrict__ wk,
    const float* __restrict__ v, const float* __restrict__ qp,
    float* __restrict__ out) {
  __shared__ __align__(16) unsigned short lds_k[64 * 512];
  __shared__ float lds_score[8][64];
  char* lds_b = (char*)lds_k;
  const int tid  = threadIdx.x;
  const int wid  = tid >> 6;
  const int lane = tid & 63;
  const int l15  = lane & 15;
  const int lhi  = lane >> 4;
  const int row0 = blockIdx.x * 64;
  const int b    = row0 >> 11;
  const int wcol = wid * 64;
  #pragma unroll
  for (int i = 0; i < 8; ++i) {
    int c = i * 512 + tid;
    int r = c >> 6, k = (c & 63) * 8;
    const float* src = keys + (size_t)(row0 + r) * 512 + k;
    const float4 f0 = *reinterpret_cast<const float4*>(src);
    const float4 f1 = *reinterpret_cast<const float4*>(src + 4);
    short8 hv;
    hv[0] = (short)f2bf(f0.x); hv[1] = (short)f2bf(f0.y);
    hv[2] = (short)f2bf(f0.z); hv[3] = (short)f2bf(f0.w);
    hv[4] = (short)f2bf(f1.x); hv[5] = (short)f2bf(f1.y);
    hv[6] = (short)f2bf(f1.z); hv[7] = (short)f2bf(f1.w);
    int byte = (r * 1024 + k * 2) ^ ((r & 7) << 4);
    *reinterpret_cast<short8*>(lds_b + byte) = hv;
  }
  __syncthreads();
  f32x4 acc[4][4];
  #pragma unroll
  for (int mr = 0; mr < 4; ++mr)
    #pragma unroll
    for (int nc = 0; nc < 4; ++nc) {
      f32x4 z = {0.f, 0.f, 0.f, 0.f};
      acc[mr][nc] = z;
    }
  const int koff = lhi * 8;
  #pragma unroll 1
  for (int k0 = 0; k0 < 512; k0 += 32) {
    short8 a[4], bbv[4];
    #pragma unroll
    for (int nc = 0; nc < 4; ++nc) {
      const unsigned short* p =
          wk + (((size_t)(wcol + nc * 16 + l15)) << 9) + k0 + koff;
      bbv[nc] = *reinterpret_cast<const short8*>(p);
    }
    #pragma unroll
    for (int mr = 0; mr < 4; ++mr) {
      int r = mr * 16 + l15;
      int byte = (r * 1024 + (k0 + koff) * 2) ^ ((r & 7) << 4);
      a[mr] = *reinterpret_cast<const short8*>(lds_b + byte);
    }
    #pragma unroll
    for (int mr = 0; mr < 4; ++mr)
      #pragma unroll
      for (int nc = 0; nc < 4; ++nc)
        acc[mr][nc] = __builtin_amdgcn_mfma_f32_16x16x32_bf16(
            a[mr], bbv[nc], acc[mr][nc], 0, 0, 0);
  }
  float rp[4][4];
  #pragma unroll
  for (int mr = 0; mr < 4; ++mr)
    #pragma unroll
    for (int j = 0; j < 4; ++j) rp[mr][j] = 0.f;
  #pragma unroll
  for (int nc = 0; nc < 4; ++nc) {
    int col = wcol + nc * 16 + l15;
    float vv = v[col];
    float qv = qp[b * 512 + col];
    #pragma unroll
    for (int mr = 0; mr < 4; ++mr)
      #pragma unroll
      for (int j = 0; j < 4; ++j)
        rp[mr][j] += fast_tanh(acc[mr][nc][j] + qv) * vv;
  }
  #pragma unroll
  for (int off = 1; off < 16; off <<= 1)
    #pragma unroll
    for (int mr = 0; mr < 4; ++mr)
      #pragma unroll
      for (int j = 0; j < 4; ++j)
        rp[mr][j] += __shfl_xor(rp[mr][j], off, 64);
  if (l15 == 0) {
    #pragma unroll
    for (int mr = 0; mr < 4; ++mr)
      #pragma unroll
      for (int j = 0; j < 4; ++j)
        lds_score[wid][mr * 16 + lhi * 4 + j] = rp[mr][j];
  }
  __syncthreads();
  if (tid < 64) {
    float s = 0.f;
    #pragma unroll
    for (int w = 0; w < 8; ++w) s += lds_score[w][tid];
    out[row0 + tid] = s;
  }
}

__global__ __launch_bounds__(512) void wsum_part_kernel(
    const float* __restrict__ keys, const float* __restrict__ attn,
    float* __restrict__ part) {
  int b = blockIdx.x, sc = blockIdx.y;
  int tid = threadIdx.x;
  int c4 = tid & 127, rg = tid >> 7;
  const float* kb = keys + ((size_t)(b * S_DIM + sc * 128 + rg * 32)) * 512 + c4 * 4;
  const float* ab = attn + b * S_DIM + sc * 128 + rg * 32;
  float4 acc = {0.f, 0.f, 0.f, 0.f};
  #pragma unroll 8
  for (int i = 0; i < 32; ++i) {
    float w = ab[i];
    float4 kv = *reinterpret_cast<const float4*>(kb + (size_t)i * 512);
    acc.x += w * kv.x; acc.y += w * kv.y; acc.z += w * kv.z; acc.w += w * kv.w;
  }
  __shared__ float4 red[4][128];
  red[rg][c4] = acc;
  __syncthreads();
  if (tid < 128) {
    float4 a0 = red[0][tid], a1 = red[1][tid], a2 = red[2][tid], a3 = red[3][tid];
    float4 s;
    s.x = a0.x + a1.x + a2.x + a3.x;
    s.y = a0.y + a1.y + a2.y + a3.y;
    s.z = a0.z + a1.z + a2.z + a3.z;
    s.w = a0.w + a1.w + a2.w + a3.w;
    *reinterpret_cast<float4*>(part + ((size_t)b * 16 + sc) * 512 + tid * 4) = s;
  }
}

__global__ __launch_bounds__(512) void wsum_final_kernel(
    const float* __restrict__ part, float* __restrict__ new_q) {
  int b = blockIdx.x, h = threadIdx.x;
  float acc = 0.f;
  #pragma unroll
  for (int sc = 0; sc < 16; ++sc) acc += part[((size_t)b * 16 + sc) * 512 + h];
  new_q[b * 512 + h] = acc;
}

// =====================  LAUNCH  =====================

extern "C" void kernel_launch(void* const* d_in, const int* in_sizes, int n_in,
                              void* d_out, int out_size, void* d_ws, size_t ws_size,
                              hipStream_t stream) {
  (void)in_sizes; (void)n_in; (void)out_size;
  const float* keys  = (const float*)d_in[0];
  const float* query = (const float*)d_in[1];
  const float* v1    = (const float*)d_in[2];
  const float* W1    = (const float*)d_in[3];
  const float* v2    = (const float*)d_in[4];
  const float* W2    = (const float*)d_in[5];
  float* out = (float*)d_out;
  float* wsf = (float*)d_ws;

  // fast-path workspace: qp1|attn|new_q|qp2 (f32) | wkp1,wkp2 (bf16) | akp (bf16)
  const size_t FAST_NEED = 491520ull * 4ull + 67108864ull * 2ull;  // ~136.2 MB
  if (ws_size >= FAST_NEED) {
    float* qp1   = wsf;                  // 32768
    float* attn  = wsf + 32768;          // 131072
    float* new_q = wsf + 163840;         // 32768
    float* qp2   = wsf + 196608;         // 32768
    unsigned short* wkp1 = (unsigned short*)(wsf + 229376);  // 262144 us
    unsigned short* wkp2 = wkp1 + 262144;                    // ends at f-off 491520
    unsigned short* akp  = (unsigned short*)(wsf + 491520);  // 67108864 us

    pack_a_kernel<<<32768, 256, 0, stream>>>(keys, akp);
    pack_b_kernel<<<256, 256, 0, stream>>>(W1, W2, wkp1, wkp2);
    qproj_kernel<<<64, 512, 0, stream>>>(W1, query, qp1);
    fused_packed_kernel<<<2048, 512, 0, stream>>>(akp, wkp1, v1, qp1, attn);
    softmax_kernel<<<64, 256, 0, stream>>>(attn);
    wsum_packed_kernel<<<dim3(64, 16), 256, 0, stream>>>(akp, attn, new_q);
    qproj_kernel<<<64, 512, 0, stream>>>(W2, new_q, qp2);
    fused_packed_kernel<<<2048, 512, 0, stream>>>(akp, wkp2, v2, qp2, out);
  } else {
    float* qp1   = wsf;
    float* attn  = wsf + 32768;
    float* new_q = wsf + 163840;
    float* qp2   = wsf + 196608;
    float* part  = wsf + 229376;
    unsigned short* wk1 = (unsigned short*)(wsf + 753664);
    unsigned short* wk2 = wk1 + 262144;

    convw_kernel<<<2048, 256, 0, stream>>>(W1, W2, wk1, wk2);
    qproj_kernel<<<64, 512, 0, stream>>>(W1, query, qp1);
    fused_scores_kernel<<<2048, 512, 0, stream>>>(keys, wk1, v1, qp1, attn);
    softmax_kernel<<<64, 256, 0, stream>>>(attn);
    wsum_part_kernel<<<dim3(64, 16), 512, 0, stream>>>(keys, attn, part);
    wsum_final_kernel<<<64, 512, 0, stream>>>(part, new_q);
    qproj_kernel<<<64, 512, 0, stream>>>(W2, new_q, qp2);
    fused_scores_kernel<<<2048, 512, 0, stream>>>(keys, wk2, v2, qp2, out);
  }
}

// Round 4
// 303.232 us; speedup vs baseline: 1.5035x; 1.0057x over previous
//
#include <hip/hip_runtime.h>
#include <cstdint>
#include <cstddef>

// B=64, S=2048, H=512.  M = B*S = 131072 rows.
#define S_DIM 2048

typedef __attribute__((ext_vector_type(8))) short short8;   // 8 bf16 = 4 VGPR
typedef __attribute__((ext_vector_type(4))) float f32x4;    // MFMA 16x16 accum

static __device__ __forceinline__ unsigned short f2bf(float f) {
  union { float f; unsigned int u; } v; v.f = f;
  unsigned int r = (v.u + 0x7fffu + ((v.u >> 16) & 1u)) >> 16;  // RNE
  return (unsigned short)r;
}

static __device__ __forceinline__ float bf2f(unsigned short u) {
  union { unsigned int u; float f; } v; v.u = ((unsigned int)u) << 16;
  return v.f;
}

static __device__ __forceinline__ float fast_tanh(float x) {
  x = fminf(15.f, fmaxf(-15.f, x));
  float e = __expf(x + x);
  return 1.f - 2.f * __builtin_amdgcn_rcpf(e + 1.f);
}

static __device__ __forceinline__ void gload_lds16(const void* g, void* l) {
  __builtin_amdgcn_global_load_lds(
      (const __attribute__((address_space(1))) void*)g,
      (__attribute__((address_space(3))) void*)l, 16, 0, 0);
}

// =====================  PACKED LAYOUTS  =====================
// Packed A (keys bf16): per 64-row tile t (2048 tiles), chunk wt in [0,4096):
//   k0 = wt>>8, mr = (wt>>6)&3, lhi = (wt>>4)&3, l15 = wt&15
//   akp[t*32768 + wt*8 + e] = keys[t*64 + mr*16 + l15][k0*32 + lhi*8 + e]
// Packed B (wk bf16): wt in [0,32768):
//   k0 = wt>>11, g = (wt>>6)&31, lhi = (wt>>4)&3, l15 = wt&15
//   wkp[wt*8 + e] = W[g*16 + l15][k0*32 + lhi*8 + e]   (keys-half, row stride 1024)

__global__ __launch_bounds__(256) void pack_b_kernel(
    const float* __restrict__ W1, const float* __restrict__ W2,
    unsigned short* __restrict__ wkp1, unsigned short* __restrict__ wkp2) {
  int j = blockIdx.x * 256 + threadIdx.x;            // 0 .. 65535
  const float* W = (j < 32768) ? W1 : W2;
  unsigned short* o = (j < 32768) ? wkp1 : wkp2;
  int wt = j & 32767;
  int k0 = wt >> 11, g = (wt >> 6) & 31, lhi = (wt >> 4) & 3, l15 = wt & 15;
  const float* src = W + (size_t)(g * 16 + l15) * 1024 + k0 * 32 + lhi * 8;
  float4 f0 = *reinterpret_cast<const float4*>(src);
  float4 f1 = *reinterpret_cast<const float4*>(src + 4);
  short8 hv;
  hv[0] = (short)f2bf(f0.x); hv[1] = (short)f2bf(f0.y);
  hv[2] = (short)f2bf(f0.z); hv[3] = (short)f2bf(f0.w);
  hv[4] = (short)f2bf(f1.x); hv[5] = (short)f2bf(f1.y);
  hv[6] = (short)f2bf(f1.z); hv[7] = (short)f2bf(f1.w);
  *reinterpret_cast<short8*>(o + (size_t)wt * 8) = hv;
}

// ---- Stage-1: read f32 keys, pack to LDS + akp, MFMA, scores. 8 waves.
__global__ __launch_bounds__(512, 4) void fused_pack_scores_kernel(
    const float* __restrict__ keys, const unsigned short* __restrict__ wkp,
    const float* __restrict__ v, const float* __restrict__ qp,
    unsigned short* __restrict__ akp, float* __restrict__ out) {
  __shared__ __align__(16) unsigned short lds_a[32768];   // 64 KB packed A tile
  __shared__ float lds_score[8][64];

  const int tid  = threadIdx.x;
  const int wid  = tid >> 6;
  const int lane = tid & 63;
  const int l15  = lane & 15;
  const int lhi  = lane >> 4;
  const int tile = blockIdx.x;
  const int row0 = tile * 64;
  const int b    = row0 >> 11;
  const int wcol = wid * 64;

  // ---- pack-stage: per thread, chunks c = i*512 + tid (decode is i-invariant
  // in the low bits: only k0 moves). LDS writes linear (conflict-free);
  // akp stores fully coalesced 16B.
  {
    const int s_mr  = (tid >> 6) & 3;
    const int s_lhi = (tid >> 4) & 3;
    const int s_l15 = tid & 15;
    const int k0_0  = tid >> 8;          // 0 or 1
    const float* srow =
        keys + (size_t)(row0 + s_mr * 16 + s_l15) * 512 + s_lhi * 8;
    unsigned short* atile = akp + (size_t)tile * 32768;
    #pragma unroll
    for (int i = 0; i < 8; ++i) {
      const int c  = i * 512 + tid;
      const int k0 = k0_0 + 2 * i;
      const float* src = srow + k0 * 32;
      float4 f0 = *reinterpret_cast<const float4*>(src);
      float4 f1 = *reinterpret_cast<const float4*>(src + 4);
      short8 hv;
      hv[0] = (short)f2bf(f0.x); hv[1] = (short)f2bf(f0.y);
      hv[2] = (short)f2bf(f0.z); hv[3] = (short)f2bf(f0.w);
      hv[4] = (short)f2bf(f1.x); hv[5] = (short)f2bf(f1.y);
      hv[6] = (short)f2bf(f1.z); hv[7] = (short)f2bf(f1.w);
      *reinterpret_cast<short8*>((char*)lds_a + c * 16) = hv;
      *reinterpret_cast<short8*>(atile + (size_t)c * 8) = hv;
    }
  }

  // prefetch B fragments for k0 = 0 (coalesced 1KB per wave per frag)
  const unsigned short* wbase = wkp + (size_t)wid * 2048 + (size_t)lane * 8;
  short8 bb[2][4];
  #pragma unroll
  for (int nc = 0; nc < 4; ++nc)
    bb[0][nc] = *reinterpret_cast<const short8*>(wbase + nc * 512);

  __syncthreads();

  f32x4 acc[4][4];
  #pragma unroll
  for (int mr = 0; mr < 4; ++mr)
    #pragma unroll
    for (int nc = 0; nc < 4; ++nc) {
      f32x4 z = {0.f, 0.f, 0.f, 0.f};
      acc[mr][nc] = z;
    }

  const char* abase = (const char*)lds_a + lane * 16;

  #pragma unroll
  for (int k0 = 0; k0 < 16; ++k0) {
    const int cur = k0 & 1, nxt = cur ^ 1;
    if (k0 < 15) {
      #pragma unroll
      for (int nc = 0; nc < 4; ++nc)
        bb[nxt][nc] = *reinterpret_cast<const short8*>(
            wbase + (size_t)(k0 + 1) * 16384 + nc * 512);
    }
    short8 a[4];
    #pragma unroll
    for (int mr = 0; mr < 4; ++mr)
      a[mr] = *reinterpret_cast<const short8*>(abase + k0 * 4096 + mr * 1024);
    #pragma unroll
    for (int mr = 0; mr < 4; ++mr)
      #pragma unroll
      for (int nc = 0; nc < 4; ++nc)
        acc[mr][nc] = __builtin_amdgcn_mfma_f32_16x16x32_bf16(
            a[mr], bb[cur][nc], acc[mr][nc], 0, 0, 0);
  }

  float rp[4][4];
  #pragma unroll
  for (int mr = 0; mr < 4; ++mr)
    #pragma unroll
    for (int j = 0; j < 4; ++j) rp[mr][j] = 0.f;

  #pragma unroll
  for (int nc = 0; nc < 4; ++nc) {
    int col = wcol + nc * 16 + l15;
    float vv = v[col];
    float qv = qp[b * 512 + col];
    #pragma unroll
    for (int mr = 0; mr < 4; ++mr)
      #pragma unroll
      for (int j = 0; j < 4; ++j)
        rp[mr][j] += fast_tanh(acc[mr][nc][j] + qv) * vv;
  }

  #pragma unroll
  for (int off = 1; off < 16; off <<= 1)
    #pragma unroll
    for (int mr = 0; mr < 4; ++mr)
      #pragma unroll
      for (int j = 0; j < 4; ++j)
        rp[mr][j] += __shfl_xor(rp[mr][j], off, 64);

  if (l15 == 0) {
    #pragma unroll
    for (int mr = 0; mr < 4; ++mr)
      #pragma unroll
      for (int j = 0; j < 4; ++j)
        lds_score[wid][mr * 16 + lhi * 4 + j] = rp[mr][j];
  }
  __syncthreads();
  if (tid < 64) {
    float s = 0.f;
    #pragma unroll
    for (int w = 0; w < 8; ++w) s += lds_score[w][tid];
    out[row0 + tid] = s;
  }
}

// ---- Stage-2: fused scores from packed operands (akp via global_load_lds).
__global__ __launch_bounds__(512, 4) void fused_packed_kernel(
    const unsigned short* __restrict__ akp, const unsigned short* __restrict__ wkp,
    const float* __restrict__ v, const float* __restrict__ qp,
    float* __restrict__ out) {
  __shared__ __align__(16) unsigned short lds_a[32768];   // 64 KB packed A tile
  __shared__ float lds_score[8][64];

  const int tid  = threadIdx.x;
  const int wid  = tid >> 6;
  const int lane = tid & 63;
  const int l15  = lane & 15;
  const int lhi  = lane >> 4;
  const int tile = blockIdx.x;
  const int row0 = tile * 64;
  const int b    = row0 >> 11;
  const int wcol = wid * 64;

  const unsigned short* atile = akp + (size_t)tile * 32768;
  #pragma unroll
  for (int i = 0; i < 8; ++i)
    gload_lds16(atile + (i * 512 + tid) * 8, (char*)lds_a + (i * 512 + tid) * 16);

  const unsigned short* wbase = wkp + (size_t)wid * 2048 + (size_t)lane * 8;
  short8 bb[2][4];
  #pragma unroll
  for (int nc = 0; nc < 4; ++nc)
    bb[0][nc] = *reinterpret_cast<const short8*>(wbase + nc * 512);

  __syncthreads();

  f32x4 acc[4][4];
  #pragma unroll
  for (int mr = 0; mr < 4; ++mr)
    #pragma unroll
    for (int nc = 0; nc < 4; ++nc) {
      f32x4 z = {0.f, 0.f, 0.f, 0.f};
      acc[mr][nc] = z;
    }

  const char* abase = (const char*)lds_a + lane * 16;

  #pragma unroll
  for (int k0 = 0; k0 < 16; ++k0) {
    const int cur = k0 & 1, nxt = cur ^ 1;
    if (k0 < 15) {
      #pragma unroll
      for (int nc = 0; nc < 4; ++nc)
        bb[nxt][nc] = *reinterpret_cast<const short8*>(
            wbase + (size_t)(k0 + 1) * 16384 + nc * 512);
    }
    short8 a[4];
    #pragma unroll
    for (int mr = 0; mr < 4; ++mr)
      a[mr] = *reinterpret_cast<const short8*>(abase + k0 * 4096 + mr * 1024);
    #pragma unroll
    for (int mr = 0; mr < 4; ++mr)
      #pragma unroll
      for (int nc = 0; nc < 4; ++nc)
        acc[mr][nc] = __builtin_amdgcn_mfma_f32_16x16x32_bf16(
            a[mr], bb[cur][nc], acc[mr][nc], 0, 0, 0);
  }

  float rp[4][4];
  #pragma unroll
  for (int mr = 0; mr < 4; ++mr)
    #pragma unroll
    for (int j = 0; j < 4; ++j) rp[mr][j] = 0.f;

  #pragma unroll
  for (int nc = 0; nc < 4; ++nc) {
    int col = wcol + nc * 16 + l15;
    float vv = v[col];
    float qv = qp[b * 512 + col];
    #pragma unroll
    for (int mr = 0; mr < 4; ++mr)
      #pragma unroll
      for (int j = 0; j < 4; ++j)
        rp[mr][j] += fast_tanh(acc[mr][nc][j] + qv) * vv;
  }

  #pragma unroll
  for (int off = 1; off < 16; off <<= 1)
    #pragma unroll
    for (int mr = 0; mr < 4; ++mr)
      #pragma unroll
      for (int j = 0; j < 4; ++j)
        rp[mr][j] += __shfl_xor(rp[mr][j], off, 64);

  if (l15 == 0) {
    #pragma unroll
    for (int mr = 0; mr < 4; ++mr)
      #pragma unroll
      for (int j = 0; j < 4; ++j)
        lds_score[wid][mr * 16 + lhi * 4 + j] = rp[mr][j];
  }
  __syncthreads();
  if (tid < 64) {
    float s = 0.f;
    #pragma unroll
    for (int w = 0; w < 8; ++w) s += lds_score[w][tid];
    out[row0 + tid] = s;
  }
}

// new_q[b][h] = sum_s attn[b,s] * keys[b,s,h], reading packed bf16 keys.
__global__ __launch_bounds__(256) void wsum_packed_kernel(
    const unsigned short* __restrict__ akp, const float* __restrict__ attn,
    float* __restrict__ new_q) {
  int b = blockIdx.x, k0 = blockIdx.y;
  int t = threadIdx.x;
  int mr = t >> 6, lhi = (t >> 4) & 3, l15 = t & 15;
  const unsigned short* base =
      akp + (size_t)b * 32 * 32768 + (size_t)k0 * 2048 + (size_t)t * 8;
  const float* ab = attn + b * S_DIM + mr * 16 + l15;
  float acc[8];
  #pragma unroll
  for (int e = 0; e < 8; ++e) acc[e] = 0.f;
  #pragma unroll 4
  for (int tile = 0; tile < 32; ++tile) {
    short8 kv = *reinterpret_cast<const short8*>(base + (size_t)tile * 32768);
    float w = ab[tile * 64];
    #pragma unroll
    for (int e = 0; e < 8; ++e)
      acc[e] += w * bf2f((unsigned short)kv[e]);
  }
  __shared__ float red[4][64][8];   // [lhi][row-slot][e]
  #pragma unroll
  for (int e = 0; e < 8; ++e) red[lhi][mr * 16 + l15][e] = acc[e];
  __syncthreads();
  if (t < 32) {
    int lh = t >> 3, e = t & 7;
    float s = 0.f;
    #pragma unroll 8
    for (int r = 0; r < 64; ++r) s += red[lh][r][e];
    new_q[b * 512 + k0 * 32 + lh * 8 + e] = s;
  }
}

// =====================  SHARED KERNELS  =====================

__global__ __launch_bounds__(512) void qproj_kernel(
    const float* __restrict__ W, const float* __restrict__ x,
    float* __restrict__ qp) {
  __shared__ float xs[512];
  int b = blockIdx.x, d = threadIdx.x;
  xs[d] = x[b * 512 + d];
  __syncthreads();
  const float4* wr = (const float4*)(W + (size_t)d * 1024 + 512);
  const float4* xv = (const float4*)xs;
  float acc = 0.f;
  #pragma unroll 8
  for (int h = 0; h < 128; ++h) {
    float4 w4 = wr[h], x4 = xv[h];
    acc += w4.x * x4.x + w4.y * x4.y + w4.z * x4.z + w4.w * x4.w;
  }
  qp[b * 512 + d] = acc;
}

__global__ __launch_bounds__(256) void softmax_kernel(float* __restrict__ sc) {
  int b = blockIdx.x, tid = threadIdx.x;
  float* row = sc + (size_t)b * S_DIM;
  float vv[8];
  float m = -1e30f;
  #pragma unroll
  for (int i = 0; i < 8; ++i) { vv[i] = row[tid + i * 256]; m = fmaxf(m, vv[i]); }
  #pragma unroll
  for (int off = 32; off; off >>= 1) m = fmaxf(m, __shfl_xor(m, off, 64));
  __shared__ float red[4], red2[4];
  int wid = tid >> 6, lane = tid & 63;
  if (lane == 0) red[wid] = m;
  __syncthreads();
  m = fmaxf(fmaxf(red[0], red[1]), fmaxf(red[2], red[3]));
  float s = 0.f;
  #pragma unroll
  for (int i = 0; i < 8; ++i) { vv[i] = __expf(vv[i] - m); s += vv[i]; }
  #pragma unroll
  for (int off = 32; off; off >>= 1) s += __shfl_xor(s, off, 64);
  if (lane == 0) red2[wid] = s;
  __syncthreads();
  s = red2[0] + red2[1] + red2[2] + red2[3];
  float inv = 1.f / s;
  #pragma unroll
  for (int i = 0; i < 8; ++i) row[tid + i * 256] = vv[i] * inv;
}

// =====================  FALLBACK PATH (round-2, f32 keys)  =====================

__global__ __launch_bounds__(256) void convw_kernel(
    const float* __restrict__ W1, const float* __restrict__ W2,
    unsigned short* __restrict__ wk1, unsigned short* __restrict__ wk2) {
  int idx = blockIdx.x * 256 + threadIdx.x;
  const float* W = (idx < 262144) ? W1 : W2;
  unsigned short* o = (idx < 262144) ? wk1 : wk2;
  int j = idx & 262143;
  int d = j >> 9, h = j & 511;
  o[j] = f2bf(W[(size_t)d * 1024 + h]);
}

__global__ __launch_bounds__(512, 4) void fused_scores_kernel(
    const float* __restrict__ keys, const unsigned short* __restrict__ wk,
    const float* __restrict__ v, const float* __restrict__ qp,
    float* __restrict__ out) {
  __shared__ __align__(16) unsigned short lds_k[64 * 512];
  __shared__ float lds_score[8][64];
  char* lds_b = (char*)lds_k;
  const int tid  = threadIdx.x;
  const int wid  = tid >> 6;
  const int lane = tid & 63;
  const int l15  = lane & 15;
  const int lhi  = lane >> 4;
  const int row0 = blockIdx.x * 64;
  const int b    = row0 >> 11;
  const int wcol = wid * 64;
  #pragma unroll
  for (int i = 0; i < 8; ++i) {
    int c = i * 512 + tid;
    int r = c >> 6, k = (c & 63) * 8;
    const float* src = keys + (size_t)(row0 + r) * 512 + k;
    const float4 f0 = *reinterpret_cast<const float4*>(src);
    const float4 f1 = *reinterpret_cast<const float4*>(src + 4);
    short8 hv;
    hv[0] = (short)f2bf(f0.x); hv[1] = (short)f2bf(f0.y);
    hv[2] = (short)f2bf(f0.z); hv[3] = (short)f2bf(f0.w);
    hv[4] = (short)f2bf(f1.x); hv[5] = (short)f2bf(f1.y);
    hv[6] = (short)f2bf(f1.z); hv[7] = (short)f2bf(f1.w);
    int byte = (r * 1024 + k * 2) ^ ((r & 7) << 4);
    *reinterpret_cast<short8*>(lds_b + byte) = hv;
  }
  __syncthreads();
  f32x4 acc[4][4];
  #pragma unroll
  for (int mr = 0; mr < 4; ++mr)
    #pragma unroll
    for (int nc = 0; nc < 4; ++nc) {
      f32x4 z = {0.f, 0.f, 0.f, 0.f};
      acc[mr][nc] = z;
    }
  const int koff = lhi * 8;
  #pragma unroll 1
  for (int k0 = 0; k0 < 512; k0 += 32) {
    short8 a[4], bbv[4];
    #pragma unroll
    for (int nc = 0; nc < 4; ++nc) {
      const unsigned short* p =
          wk + (((size_t)(wcol + nc * 16 + l15)) << 9) + k0 + koff;
      bbv[nc] = *reinterpret_cast<const short8*>(p);
    }
    #pragma unroll
    for (int mr = 0; mr < 4; ++mr) {
      int r = mr * 16 + l15;
      int byte = (r * 1024 + (k0 + koff) * 2) ^ ((r & 7) << 4);
      a[mr] = *reinterpret_cast<const short8*>(lds_b + byte);
    }
    #pragma unroll
    for (int mr = 0; mr < 4; ++mr)
      #pragma unroll
      for (int nc = 0; nc < 4; ++nc)
        acc[mr][nc] = __builtin_amdgcn_mfma_f32_16x16x32_bf16(
            a[mr], bbv[nc], acc[mr][nc], 0, 0, 0);
  }
  float rp[4][4];
  #pragma unroll
  for (int mr = 0; mr < 4; ++mr)
    #pragma unroll
    for (int j = 0; j < 4; ++j) rp[mr][j] = 0.f;
  #pragma unroll
  for (int nc = 0; nc < 4; ++nc) {
    int col = wcol + nc * 16 + l15;
    float vv = v[col];
    float qv = qp[b * 512 + col];
    #pragma unroll
    for (int mr = 0; mr < 4; ++mr)
      #pragma unroll
      for (int j = 0; j < 4; ++j)
        rp[mr][j] += fast_tanh(acc[mr][nc][j] + qv) * vv;
  }
  #pragma unroll
  for (int off = 1; off < 16; off <<= 1)
    #pragma unroll
    for (int mr = 0; mr < 4; ++mr)
      #pragma unroll
      for (int j = 0; j < 4; ++j)
        rp[mr][j] += __shfl_xor(rp[mr][j], off, 64);
  if (l15 == 0) {
    #pragma unroll
    for (int mr = 0; mr < 4; ++mr)
      #pragma unroll
      for (int j = 0; j < 4; ++j)
        lds_score[wid][mr * 16 + lhi * 4 + j] = rp[mr][j];
  }
  __syncthreads();
  if (tid < 64) {
    float s = 0.f;
    #pragma unroll
    for (int w = 0; w < 8; ++w) s += lds_score[w][tid];
    out[row0 + tid] = s;
  }
}

__global__ __launch_bounds__(512) void wsum_part_kernel(
    const float* __restrict__ keys, const float* __restrict__ attn,
    float* __restrict__ part) {
  int b = blockIdx.x, sc = blockIdx.y;
  int tid = threadIdx.x;
  int c4 = tid & 127, rg = tid >> 7;
  const float* kb = keys + ((size_t)(b * S_DIM + sc * 128 + rg * 32)) * 512 + c4 * 4;
  const float* ab = attn + b * S_DIM + sc * 128 + rg * 32;
  float4 acc = {0.f, 0.f, 0.f, 0.f};
  #pragma unroll 8
  for (int i = 0; i < 32; ++i) {
    float w = ab[i];
    float4 kv = *reinterpret_cast<const float4*>(kb + (size_t)i * 512);
    acc.x += w * kv.x; acc.y += w * kv.y; acc.z += w * kv.z; acc.w += w * kv.w;
  }
  __shared__ float4 red[4][128];
  red[rg][c4] = acc;
  __syncthreads();
  if (tid < 128) {
    float4 a0 = red[0][tid], a1 = red[1][tid], a2 = red[2][tid], a3 = red[3][tid];
    float4 s;
    s.x = a0.x + a1.x + a2.x + a3.x;
    s.y = a0.y + a1.y + a2.y + a3.y;
    s.z = a0.z + a1.z + a2.z + a3.z;
    s.w = a0.w + a1.w + a2.w + a3.w;
    *reinterpret_cast<float4*>(part + ((size_t)b * 16 + sc) * 512 + tid * 4) = s;
  }
}

__global__ __launch_bounds__(512) void wsum_final_kernel(
    const float* __restrict__ part, float* __restrict__ new_q) {
  int b = blockIdx.x, h = threadIdx.x;
  float acc = 0.f;
  #pragma unroll
  for (int sc = 0; sc < 16; ++sc) acc += part[((size_t)b * 16 + sc) * 512 + h];
  new_q[b * 512 + h] = acc;
}

// =====================  LAUNCH  =====================

extern "C" void kernel_launch(void* const* d_in, const int* in_sizes, int n_in,
                              void* d_out, int out_size, void* d_ws, size_t ws_size,
                              hipStream_t stream) {
  (void)in_sizes; (void)n_in; (void)out_size;
  const float* keys  = (const float*)d_in[0];
  const float* query = (const float*)d_in[1];
  const float* v1    = (const float*)d_in[2];
  const float* W1    = (const float*)d_in[3];
  const float* v2    = (const float*)d_in[4];
  const float* W2    = (const float*)d_in[5];
  float* out = (float*)d_out;
  float* wsf = (float*)d_ws;

  // fast-path workspace: qp1|attn|new_q|qp2 (f32) | wkp1,wkp2 (bf16) | akp (bf16)
  const size_t FAST_NEED = 491520ull * 4ull + 67108864ull * 2ull;  // ~136.2 MB
  if (ws_size >= FAST_NEED) {
    float* qp1   = wsf;                  // 32768
    float* attn  = wsf + 32768;          // 131072
    float* new_q = wsf + 163840;         // 32768
    float* qp2   = wsf + 196608;         // 32768
    unsigned short* wkp1 = (unsigned short*)(wsf + 229376);  // 262144 us
    unsigned short* wkp2 = wkp1 + 262144;                    // ends at f-off 491520
    unsigned short* akp  = (unsigned short*)(wsf + 491520);  // 67108864 us

    pack_b_kernel<<<256, 256, 0, stream>>>(W1, W2, wkp1, wkp2);
    qproj_kernel<<<64, 512, 0, stream>>>(W1, query, qp1);
    fused_pack_scores_kernel<<<2048, 512, 0, stream>>>(keys, wkp1, v1, qp1, akp, attn);
    softmax_kernel<<<64, 256, 0, stream>>>(attn);
    wsum_packed_kernel<<<dim3(64, 16), 256, 0, stream>>>(akp, attn, new_q);
    qproj_kernel<<<64, 512, 0, stream>>>(W2, new_q, qp2);
    fused_packed_kernel<<<2048, 512, 0, stream>>>(akp, wkp2, v2, qp2, out);
  } else {
    float* qp1   = wsf;
    float* attn  = wsf + 32768;
    float* new_q = wsf + 163840;
    float* qp2   = wsf + 196608;
    float* part  = wsf + 229376;
    unsigned short* wk1 = (unsigned short*)(wsf + 753664);
    unsigned short* wk2 = wk1 + 262144;

    convw_kernel<<<2048, 256, 0, stream>>>(W1, W2, wk1, wk2);
    qproj_kernel<<<64, 512, 0, stream>>>(W1, query, qp1);
    fused_scores_kernel<<<2048, 512, 0, stream>>>(keys, wk1, v1, qp1, attn);
    softmax_kernel<<<64, 256, 0, stream>>>(attn);
    wsum_part_kernel<<<dim3(64, 16), 512, 0, stream>>>(keys, attn, part);
    wsum_final_kernel<<<64, 512, 0, stream>>>(part, new_q);
    qproj_kernel<<<64, 512, 0, stream>>>(W2, new_q, qp2);
    fused_scores_kernel<<<2048, 512, 0, stream>>>(keys, wk2, v2, qp2, out);
  }
}